// Round 6
// baseline (5294.966 us; speedup 1.0000x reference)
//
#include <hip/hip_runtime.h>

// Hetero-SAGE 2-layer forward, MI355X — bf16 data path + MFMA GEMM.
// Round-5: bucket-grouped aggregation (no exact CSR). Per direction:
//   hist (per-dst cnt, mean divisor) -> bucket sums (3125 x 32-dst) ->
//   single-block scan -> bucketA (4B packed src|dstlane appends) ->
//   agg_bucket: block per bucket, 32x128 f32 LDS accum, 4-deep gather ILP.
// Removes bucketB + 100k-element scans (round-4 rocprof: bucketA WRITE 92MB
// line-bounce amp; agg latency-bound at 2-deep ILP).

#define NN 100000
#define EE 1600000
#define NB 3125          // dst buckets of 32 rows each (100000/32)

typedef unsigned int uint32;
typedef __attribute__((ext_vector_type(8))) short short8;
typedef __attribute__((ext_vector_type(4))) float f32x4;

__device__ __forceinline__ unsigned short f2bf(float f) {
    unsigned u = __float_as_uint(f);
    return (unsigned short)((u + 0x7fffu + ((u >> 16) & 1u)) >> 16);  // RNE
}
__device__ __forceinline__ uint32 pk2(float a, float b) {
    return (uint32)f2bf(a) | ((uint32)f2bf(b) << 16);
}
__device__ __forceinline__ float bl(uint32 u) { return __uint_as_float(u << 16); }
__device__ __forceinline__ float bh(uint32 u) { return __uint_as_float(u & 0xffff0000u); }

// ---------------- prep: fp32 -> bf16 (8 elems/thread) ----------------
__global__ void f2b_kernel(const float* __restrict__ src, unsigned short* __restrict__ dst, int n8) {
    int i = blockIdx.x * 256 + threadIdx.x;
    if (i >= n8) return;
    float4 v0 = ((const float4*)src)[(size_t)i * 2];
    float4 v1 = ((const float4*)src)[(size_t)i * 2 + 1];
    uint4 o;
    o.x = pk2(v0.x, v0.y); o.y = pk2(v0.z, v0.w);
    o.z = pk2(v1.x, v1.y); o.w = pk2(v1.z, v1.w);
    ((uint4*)dst)[i] = o;
}

// ---------------- prep: W[k][n] fp32 -> Wt[n][k] bf16, 8 matrices ----------------
__global__ void prep_w(const float* w0, const float* w1, const float* w2, const float* w3,
                       const float* w4, const float* w5, const float* w6, const float* w7,
                       unsigned short* __restrict__ wt) {
    const float* ws[8] = {w0, w1, w2, w3, w4, w5, w6, w7};
    const float* W = ws[blockIdx.y];
    unsigned short* Wt = wt + (size_t)blockIdx.y * 16384;
    int idx = blockIdx.x * 256 + threadIdx.x;   // 64 x-blocks * 256 = 16384
    int n = idx >> 7, k = idx & 127;
    Wt[n * 128 + k] = f2bf(W[(size_t)k * 128 + n]);
}

// ---------------- edge indexing ----------------
__global__ void hist_kernel(const int* __restrict__ ei, int* __restrict__ cnt, int E) {
    int i = blockIdx.x * blockDim.x + threadIdx.x;
    if (i < E) atomicAdd(&cnt[ei[E + i]], 1);
}

__global__ void bucketsum(const int* __restrict__ cnt, int* __restrict__ bsum) {
    int b = blockIdx.x * 256 + threadIdx.x;
    if (b >= NB) return;
    int s = 0;
#pragma unroll
    for (int k = 0; k < 32; k++) s += cnt[b * 32 + k];
    bsum[b] = s;
}

// single-block exclusive scan over NB=3125 bucket sums
__global__ void bscan(const int* __restrict__ bsum, int* __restrict__ boff) {
    __shared__ int s[256];
    int t = threadIdx.x;
    int base_i = t * 13;                 // 256*13 = 3328 >= 3125
    int loc[13]; int tv = 0;
#pragma unroll
    for (int k = 0; k < 13; k++) {
        int i = base_i + k;
        int v = (i < NB) ? bsum[i] : 0;
        loc[k] = v; tv += v;
    }
    s[t] = tv; __syncthreads();
    for (int d = 1; d < 256; d <<= 1) {
        int x = (t >= d) ? s[t - d] : 0;
        __syncthreads();
        s[t] += x;
        __syncthreads();
    }
    int ex = s[t] - tv;
#pragma unroll
    for (int k = 0; k < 13; k++) {
        int i = base_i + k;
        if (i < NB) boff[i] = ex;
        ex += loc[k];
    }
    if (t == 255) boff[NB] = s[255];
}

__global__ void bcur_init(const int* __restrict__ boff, int* __restrict__ bcur) {
    int b = blockIdx.x * 256 + threadIdx.x;
    if (b < NB) bcur[b * 16] = boff[b];   // one cursor per 64B line
}

// append packed (src | (dst&31)<<17) to the dst's 32-row bucket region
__global__ void bucketA(const int* __restrict__ ei, int* __restrict__ bcur,
                        uint32* __restrict__ tmp, int E) {
    int i = blockIdx.x * blockDim.x + threadIdx.x;
    if (i < E) {
        uint32 s = (uint32)ei[i];
        int d = ei[E + i];
        int p = atomicAdd(&bcur[(d >> 5) * 16], 1);
        tmp[p] = s | ((uint32)(d & 31) << 17);
    }
}

// ---------------- bucket-accumulated mean aggregation ----------------
// One block per 32-dst bucket. 32x128 fp32 accum in LDS; 4 waves each
// process 4 edges per iteration (16 gathers in flight per block).
__global__ __launch_bounds__(256) void agg_bucket(
        const uint32* __restrict__ Xu, const uint32* __restrict__ tmp,
        const int* __restrict__ boff, const int* __restrict__ cnt,
        uint32* __restrict__ out) {
    __shared__ float acc[4096];          // [32 rows][128 cols]
    int t = threadIdx.x;
    int b = blockIdx.x;
#pragma unroll
    for (int i = 0; i < 16; i++) acc[t + i * 256] = 0.f;
    __syncthreads();
    int o0 = boff[b], o1 = boff[b + 1];
    int lane = t & 63, wv = t >> 6;
    int n = o1 - o0;
    int nmain = n & ~15;
    for (int j = o0 + wv * 4; j + 4 <= o0 + nmain; j += 16) {
        uint32 p0 = tmp[j], p1 = tmp[j + 1], p2 = tmp[j + 2], p3 = tmp[j + 3];
        uint32 v0 = Xu[(size_t)(p0 & 0x1ffff) * 64 + lane];
        uint32 v1 = Xu[(size_t)(p1 & 0x1ffff) * 64 + lane];
        uint32 v2 = Xu[(size_t)(p2 & 0x1ffff) * 64 + lane];
        uint32 v3 = Xu[(size_t)(p3 & 0x1ffff) * 64 + lane];
        int r0 = (int)(p0 >> 17) << 7, r1 = (int)(p1 >> 17) << 7;
        int r2 = (int)(p2 >> 17) << 7, r3 = (int)(p3 >> 17) << 7;
        atomicAdd(&acc[r0 + 2 * lane], bl(v0));
        atomicAdd(&acc[r0 + 2 * lane + 1], bh(v0));
        atomicAdd(&acc[r1 + 2 * lane], bl(v1));
        atomicAdd(&acc[r1 + 2 * lane + 1], bh(v1));
        atomicAdd(&acc[r2 + 2 * lane], bl(v2));
        atomicAdd(&acc[r2 + 2 * lane + 1], bh(v2));
        atomicAdd(&acc[r3 + 2 * lane], bl(v3));
        atomicAdd(&acc[r3 + 2 * lane + 1], bh(v3));
    }
    for (int e = o0 + nmain + wv; e < o1; e += 4) {
        uint32 p = tmp[e];
        uint32 v = Xu[(size_t)(p & 0x1ffff) * 64 + lane];
        int r = (int)(p >> 17) << 7;
        atomicAdd(&acc[r + 2 * lane], bl(v));
        atomicAdd(&acc[r + 2 * lane + 1], bh(v));
    }
    __syncthreads();
    int row = t >> 3;                    // 0..31
    int c0 = (t & 7) * 8;                // uint32-col base, 8 per thread
    float inv = 1.0f / fmaxf((float)cnt[b * 32 + row], 1.0f);
    uint32* orow = &out[((size_t)b * 32 + row) * 64 + c0];
#pragma unroll
    for (int k = 0; k < 8; k++) {
        float x0 = acc[row * 128 + (c0 + k) * 2] * inv;
        float x1 = acc[row * 128 + (c0 + k) * 2 + 1] * inv;
        orow[k] = pk2(x0, x1);
    }
}

// ---------------- MFMA GEMM: out = A1@W1 + A2@W2 + bias ----------------
// A1,A2: [M][128] bf16; Wt1,Wt2: [128 n][128 k] bf16 (pre-transposed).
// Block: 256 thr = 4 waves (2x2), tile 128m x 128n, BK=64, 4 K-steps.
// LDS XOR-swizzle (G4): byte ^= ((row&7)<<4) -> conflict-free ds_read_b128.
template<bool OBF>
__global__ __launch_bounds__(256) void gemm_bf16(
        const unsigned short* __restrict__ A1, const unsigned short* __restrict__ A2,
        const unsigned short* __restrict__ Wt1, const unsigned short* __restrict__ Wt2,
        const float* __restrict__ bias, void* __restrict__ outp, int M) {
    __shared__ unsigned short As[128 * 64];
    __shared__ unsigned short Bs[128 * 64];
    int t = threadIdx.x;
    int m0 = blockIdx.x * 128;
    int lane = t & 63;
    int wid = t >> 6;
    int wr = wid >> 1, wc = wid & 1;

    f32x4 acc[4][4];
#pragma unroll
    for (int i = 0; i < 4; i++)
#pragma unroll
        for (int j = 0; j < 4; j++) acc[i][j] = (f32x4){0.f, 0.f, 0.f, 0.f};

    int rs = t >> 3;     // staging row base 0..31
    int gs = t & 7;      // staging 16B k-group
    uint4 arg[2][4], brg[2][4];

    // prologue: load + write K-step 0  (A1, kc=0)
#pragma unroll
    for (int j = 0; j < 4; j++) {
        int row = rs + j * 32;
        int mrow = m0 + row; if (mrow >= M) mrow = M - 1;
        arg[0][j] = *(const uint4*)&A1[(size_t)mrow * 128 + gs * 8];
        brg[0][j] = *(const uint4*)&Wt1[(size_t)row * 128 + gs * 8];
    }
#pragma unroll
    for (int j = 0; j < 4; j++) {
        int row = rs + j * 32;
        int o = row * 64 + ((gs ^ (row & 7)) << 3);
        *(uint4*)&As[o] = arg[0][j];
        *(uint4*)&Bs[o] = brg[0][j];
    }
    __syncthreads();

    for (int ks = 0; ks < 4; ks++) {
        int nxt = (ks + 1) & 1;
        if (ks < 3) {  // prefetch next step's global tiles into regs
            const unsigned short* A  = (ks >= 1) ? A2 : A1;
            const unsigned short* Wt = (ks >= 1) ? Wt2 : Wt1;
            int kc = ((ks + 1) & 1) * 64;
#pragma unroll
            for (int j = 0; j < 4; j++) {
                int row = rs + j * 32;
                int mrow = m0 + row; if (mrow >= M) mrow = M - 1;
                arg[nxt][j] = *(const uint4*)&A[(size_t)mrow * 128 + kc + gs * 8];
                brg[nxt][j] = *(const uint4*)&Wt[(size_t)row * 128 + kc + gs * 8];
            }
        }
        // compute current K-step (64 k = 2 MFMA k-slices)
#pragma unroll
        for (int kk = 0; kk < 2; kk++) {
            short8 af[4], bfr[4];
            int g = kk * 4 + (lane >> 4);
#pragma unroll
            for (int x = 0; x < 4; x++) {
                int row = wr * 64 + x * 16 + (lane & 15);
                af[x] = *(const short8*)&As[row * 64 + ((g ^ (row & 7)) << 3)];
                int nr = wc * 64 + x * 16 + (lane & 15);
                bfr[x] = *(const short8*)&Bs[nr * 64 + ((g ^ (nr & 7)) << 3)];
            }
#pragma unroll
            for (int mi = 0; mi < 4; mi++)
#pragma unroll
                for (int ni = 0; ni < 4; ni++)
                    acc[mi][ni] = __builtin_amdgcn_mfma_f32_16x16x32_bf16(
                        af[mi], bfr[ni], acc[mi][ni], 0, 0, 0);
        }
        __syncthreads();
        if (ks < 3) {
#pragma unroll
            for (int j = 0; j < 4; j++) {
                int row = rs + j * 32;
                int o = row * 64 + ((gs ^ (row & 7)) << 3);
                *(uint4*)&As[o] = arg[nxt][j];
                *(uint4*)&Bs[o] = brg[nxt][j];
            }
            __syncthreads();
        }
    }

    float br_[4];
#pragma unroll
    for (int ni = 0; ni < 4; ni++) br_[ni] = bias[wc * 64 + ni * 16 + (lane & 15)];
#pragma unroll
    for (int mi = 0; mi < 4; mi++) {
        int mbase = m0 + wr * 64 + mi * 16 + ((lane >> 4) << 2);
#pragma unroll
        for (int i = 0; i < 4; i++) {
            int m = mbase + i;
            if (m < M) {
#pragma unroll
                for (int ni = 0; ni < 4; ni++) {
                    int n = wc * 64 + ni * 16 + (lane & 15);
                    float v = acc[mi][ni][i] + br_[ni];
                    if (OBF) ((unsigned short*)outp)[(size_t)m * 128 + n] = f2bf(v);
                    else     ((float*)outp)[(size_t)m * 128 + n] = v;
                }
            }
        }
    }
}

// ---------------- BatchNorm statistics over bf16 h ----------------
__global__ void bn_stats(const uint32* __restrict__ h, float* __restrict__ part, int N) {
    int t = threadIdx.x;
    int p = t & 63;       // col-pair (2 bf16 per uint)
    int rh = t >> 6;      // 4 row groups
    float s0 = 0.f, s1 = 0.f, q0 = 0.f, q1 = 0.f;
    for (int r = blockIdx.x * 4 + rh; r < N; r += gridDim.x * 4) {
        uint32 v = h[(size_t)r * 64 + p];
        float x0 = bl(v), x1 = bh(v);
        s0 += x0; s1 += x1; q0 += x0 * x0; q1 += x1 * x1;
    }
    __shared__ float ls[256];
    float* po = &part[(size_t)blockIdx.x * 256];
    ls[t] = s0; __syncthreads();
    if (t < 64) po[2 * t] = ls[t] + ls[t + 64] + ls[t + 128] + ls[t + 192];
    __syncthreads();
    ls[t] = s1; __syncthreads();
    if (t < 64) po[2 * t + 1] = ls[t] + ls[t + 64] + ls[t + 128] + ls[t + 192];
    __syncthreads();
    ls[t] = q0; __syncthreads();
    if (t < 64) po[128 + 2 * t] = ls[t] + ls[t + 64] + ls[t + 128] + ls[t + 192];
    __syncthreads();
    ls[t] = q1; __syncthreads();
    if (t < 64) po[128 + 2 * t + 1] = ls[t] + ls[t + 64] + ls[t + 128] + ls[t + 192];
}

__global__ void bn_reduce(const float* __restrict__ part, float* __restrict__ stat, int nb) {
    int t = threadIdx.x;  // 256
    float s = 0.f;
    for (int b = 0; b < nb; b++) s += part[(size_t)b * 256 + t];
    stat[t] = s;
}

// ---------------- fused BN + LeakyReLU + row L2 norm (bf16 in/out) ----------------
__global__ void bn_apply(uint32* __restrict__ h, const float* __restrict__ stat,
                         const float* __restrict__ g, const float* __restrict__ be, int N) {
    int w = blockIdx.x * 4 + (threadIdx.x >> 6);
    if (w >= N) return;
    int lane = threadIdx.x & 63;
    int c0 = lane * 2;
    float invN = 1.0f / (float)N;
    float mu0 = stat[c0] * invN, mu1 = stat[c0 + 1] * invN;
    float v0 = stat[128 + c0] * invN - mu0 * mu0;
    float v1 = stat[128 + c0 + 1] * invN - mu1 * mu1;
    float rs0 = rsqrtf(v0 + 1e-5f), rs1 = rsqrtf(v1 + 1e-5f);
    float g0 = g[c0], g1 = g[c0 + 1], b0 = be[c0], b1 = be[c0 + 1];
    uint32 xv = h[(size_t)w * 64 + lane];
    float y0 = (bl(xv) - mu0) * rs0 * g0 + b0;
    float y1 = (bh(xv) - mu1) * rs1 * g1 + b1;
    y0 = (y0 >= 0.f) ? y0 : 0.01f * y0;
    y1 = (y1 >= 0.f) ? y1 : 0.01f * y1;
    float q = y0 * y0 + y1 * y1;
#pragma unroll
    for (int d = 1; d < 64; d <<= 1) q += __shfl_xor(q, d);
    float inv = 1.0f / fmaxf(sqrtf(q), 1e-12f);
    h[(size_t)w * 64 + lane] = pk2(y0 * inv, y1 * inv);
}

// ---------------- plain row L2 norm (fp32 d_out) ----------------
__global__ void l2_kernel(float* __restrict__ o, int N) {
    int w = blockIdx.x * 4 + (threadIdx.x >> 6);
    if (w >= N) return;
    int lane = threadIdx.x & 63;
    float2 x = ((float2*)o)[(size_t)w * 64 + lane];
    float q = x.x * x.x + x.y * x.y;
#pragma unroll
    for (int d = 1; d < 64; d <<= 1) q += __shfl_xor(q, d);
    float inv = 1.0f / fmaxf(sqrtf(q), 1e-12f);
    x.x *= inv; x.y *= inv;
    ((float2*)o)[(size_t)w * 64 + lane] = x;
}

extern "C" void kernel_launch(void* const* d_in, const int* in_sizes, int n_in,
                              void* d_out, int out_size, void* d_ws, size_t ws_size,
                              hipStream_t stream) {
    const float* x_a    = (const float*)d_in[0];
    const float* x_b    = (const float*)d_in[1];
    const int*   ei_ab  = (const int*)d_in[2];
    const int*   ei_ba  = (const int*)d_in[3];
    const float* W0ab_m = (const float*)d_in[4];
    const float* b0ab   = (const float*)d_in[5];
    const float* W0ab_s = (const float*)d_in[6];
    const float* W0ba_m = (const float*)d_in[7];
    const float* b0ba   = (const float*)d_in[8];
    const float* W0ba_s = (const float*)d_in[9];
    const float* g0a    = (const float*)d_in[10];
    const float* be0a   = (const float*)d_in[11];
    const float* g0b    = (const float*)d_in[12];
    const float* be0b   = (const float*)d_in[13];
    const float* W1ab_m = (const float*)d_in[14];
    const float* b1ab   = (const float*)d_in[15];
    const float* W1ab_s = (const float*)d_in[16];
    const float* W1ba_m = (const float*)d_in[17];
    const float* b1ba   = (const float*)d_in[18];
    const float* W1ba_s = (const float*)d_in[19];

    char* ws = (char*)d_ws;
    size_t p = 0;
    auto alloc = [&](size_t bytes) -> char* {
        char* r = ws + p;
        p += (bytes + 255) & ~(size_t)255;
        return r;
    };
    unsigned short* h_a  = (unsigned short*)alloc((size_t)NN * 128 * 2);  // bf16
    unsigned short* h_b  = (unsigned short*)alloc((size_t)NN * 128 * 2);
    unsigned short* xb_a = (unsigned short*)alloc((size_t)NN * 128 * 2);  // reused as agg1_a
    unsigned short* xb_b = (unsigned short*)alloc((size_t)NN * 128 * 2);  // reused as agg1_b
    uint32* tmp_ab = (uint32*)alloc((size_t)EE * 4);  // packed bucket entries
    uint32* tmp_ba = (uint32*)alloc((size_t)EE * 4);
    int*   cnt_ab  = (int*)alloc(NN * 4);             // per-dst degree (divisor)
    int*   cnt_ba  = (int*)alloc(NN * 4);
    int*   bsum_ab = (int*)alloc(NB * 4);
    int*   bsum_ba = (int*)alloc(NB * 4);
    int*   boff_ab = (int*)alloc((NB + 1) * 4);
    int*   boff_ba = (int*)alloc((NB + 1) * 4);
    int*   bcur    = (int*)alloc((size_t)NB * 16 * 4);
    unsigned short* Wt = (unsigned short*)alloc((size_t)8 * 16384 * 2);
    float* bnpart  = (float*)alloc(200 * 256 * 4);
    float* stat    = (float*)alloc(256 * 4);

    // layer-0 agg buffers (bf16) live in d_out (102 MB fp32, unused until L1 GEMM)
    uint32* agg0_a = (uint32*)d_out;
    uint32* agg0_b = (uint32*)((char*)d_out + (size_t)NN * 128 * 2);
    uint32* agg1_a = (uint32*)xb_a;
    uint32* agg1_b = (uint32*)xb_b;

    // ---- prep: bf16 conversions ----
    f2b_kernel<<<6250, 256, 0, stream>>>(x_a, xb_a, NN * 128 / 8);
    f2b_kernel<<<6250, 256, 0, stream>>>(x_b, xb_b, NN * 128 / 8);
    prep_w<<<dim3(64, 8), 256, 0, stream>>>(W0ab_m, W0ab_s, W0ba_m, W0ba_s,
                                            W1ab_m, W1ab_s, W1ba_m, W1ba_s, Wt);
    unsigned short* Wt0ab_m = Wt;
    unsigned short* Wt0ab_s = Wt + 16384;
    unsigned short* Wt0ba_m = Wt + 2 * 16384;
    unsigned short* Wt0ba_s = Wt + 3 * 16384;
    unsigned short* Wt1ab_m = Wt + 4 * 16384;
    unsigned short* Wt1ab_s = Wt + 5 * 16384;
    unsigned short* Wt1ba_m = Wt + 6 * 16384;
    unsigned short* Wt1ba_s = Wt + 7 * 16384;

    // ---- bucket-grouped edge build (both directions) ----
    hipMemsetAsync(cnt_ab, 0, NN * 4, stream);
    hipMemsetAsync(cnt_ba, 0, NN * 4, stream);
    hist_kernel<<<6250, 256, 0, stream>>>(ei_ab, cnt_ab, EE);
    hist_kernel<<<6250, 256, 0, stream>>>(ei_ba, cnt_ba, EE);
    bucketsum<<<13, 256, 0, stream>>>(cnt_ab, bsum_ab);
    bucketsum<<<13, 256, 0, stream>>>(cnt_ba, bsum_ba);
    bscan<<<1, 256, 0, stream>>>(bsum_ab, boff_ab);
    bscan<<<1, 256, 0, stream>>>(bsum_ba, boff_ba);
    bcur_init<<<13, 256, 0, stream>>>(boff_ab, bcur);
    bucketA<<<6250, 256, 0, stream>>>(ei_ab, bcur, tmp_ab, EE);
    bcur_init<<<13, 256, 0, stream>>>(boff_ba, bcur);
    bucketA<<<6250, 256, 0, stream>>>(ei_ba, bcur, tmp_ba, EE);

    // ---- layer 0 ----
    agg_bucket<<<NB, 256, 0, stream>>>((const uint32*)xb_b, tmp_ba, boff_ba, cnt_ba, agg0_a);
    agg_bucket<<<NB, 256, 0, stream>>>((const uint32*)xb_a, tmp_ab, boff_ab, cnt_ab, agg0_b);
    gemm_bf16<true><<<782, 256, 0, stream>>>((const unsigned short*)agg0_a, xb_a,
                                             Wt0ba_m, Wt0ba_s, b0ba, h_a, NN);
    gemm_bf16<true><<<782, 256, 0, stream>>>((const unsigned short*)agg0_b, xb_b,
                                             Wt0ab_m, Wt0ab_s, b0ab, h_b, NN);
    bn_stats<<<200, 256, 0, stream>>>((const uint32*)h_a, bnpart, NN);
    bn_reduce<<<1, 256, 0, stream>>>(bnpart, stat, 200);
    bn_apply<<<25000, 256, 0, stream>>>((uint32*)h_a, stat, g0a, be0a, NN);
    bn_stats<<<200, 256, 0, stream>>>((const uint32*)h_b, bnpart, NN);
    bn_reduce<<<1, 256, 0, stream>>>(bnpart, stat, 200);
    bn_apply<<<25000, 256, 0, stream>>>((uint32*)h_b, stat, g0b, be0b, NN);

    // ---- layer 1 ----
    agg_bucket<<<NB, 256, 0, stream>>>((const uint32*)h_b, tmp_ba, boff_ba, cnt_ba, agg1_a);
    agg_bucket<<<NB, 256, 0, stream>>>((const uint32*)h_a, tmp_ab, boff_ab, cnt_ab, agg1_b);
    gemm_bf16<false><<<782, 256, 0, stream>>>((const unsigned short*)agg1_a, h_a,
                                              Wt1ba_m, Wt1ba_s, b1ba, (float*)d_out, NN);
    gemm_bf16<false><<<782, 256, 0, stream>>>((const unsigned short*)agg1_b, h_b,
                                              Wt1ab_m, Wt1ab_s, b1ab,
                                              (float*)d_out + (size_t)NN * 128, NN);
    l2_kernel<<<50000, 256, 0, stream>>>((float*)d_out, 2 * NN);
}